// Round 5
// baseline (494.334 us; speedup 1.0000x reference)
//
#include <hip/hip_runtime.h>

#define NN 50000
#define NE 1600000
#define NBH 128            // deghist edge chunks
#define CHE (NE / NBH)     // 12500 edges/chunk
#define HALF 25000         // nodes per histogram half
#define NPB 64             // nodes per bin
#define NBIN 782           // ceil(NN / NPB); last bin has 16 valid nodes
#define WBLK 256           // binwrite blocks
#define EPB (NE / WBLK)    // 6250 edges/block

// ---------------- workspace layout (floats) ----------------
// er[2*NE] | deg[NN] | gbincnt[NBIN] | dinv[NN] | binstart[NBIN+1] | bincur[NBIN]
// | Mz[1024] | Mh[1024] | cz[32] | ch[32]     total ~= 13.3 MB
// memset: deg..gbincnt contiguous (NN+NBIN)*4 bytes.

// deg via LDS weight-histogram (2 halves x 128 chunks); p==0 blocks also
// count edges per dst-bin. All global atomics are dense+coalesced flushes.
__global__ __launch_bounds__(1024) void k_deghist(const int* __restrict__ ei,
                                                  const float* __restrict__ ew,
                                                  float* __restrict__ deg,
                                                  unsigned* __restrict__ gbincnt) {
    __shared__ float hist[HALF];     // 100 KB
    __shared__ unsigned bcnt[NBIN];  // 3.1 KB
    int p = blockIdx.x >> 7;
    int c = blockIdx.x & 127;
    int base = p * HALF;
    for (int i = threadIdx.x; i < HALF; i += 1024) hist[i] = 0.f;
    if (p == 0)
        for (int i = threadIdx.x; i < NBIN; i += 1024) bcnt[i] = 0u;
    __syncthreads();
    int lo = c * CHE, hi = lo + CHE;
    for (int e = lo + threadIdx.x; e < hi; e += 1024) {
        int d = ei[NE + e];
        if (p == 0) atomicAdd(&bcnt[d >> 6], 1u);          // LDS
        unsigned r = (unsigned)(d - base);
        if (r < HALF) atomicAdd(&hist[r], ew[e]);          // LDS
    }
    __syncthreads();
    for (int i = threadIdx.x; i < HALF; i += 1024)
        atomicAdd(&deg[base + i], hist[i]);                // dense coalesced
    if (p == 0)
        for (int i = threadIdx.x; i < NBIN; i += 1024)
            atomicAdd(&gbincnt[i], bcnt[i]);               // dense coalesced
}

// Three roles in one launch: dinv (b<196) | bin-offset scan (b==196) | weight
// folding Mz=Wz@Lzw_top etc. (b==197). H0=0 kills R gate + bottom gate halves.
__global__ __launch_bounds__(256) void k_mid(
        const float* __restrict__ deg, float* __restrict__ dinv,
        const unsigned* __restrict__ gbincnt, unsigned* __restrict__ binstart,
        unsigned* __restrict__ bincur,
        const float* __restrict__ Wz, const float* __restrict__ Lzw,
        const float* __restrict__ bz, const float* __restrict__ Lzb,
        const float* __restrict__ Wh, const float* __restrict__ Lhw,
        const float* __restrict__ bh, const float* __restrict__ Lhb,
        float* __restrict__ Mz, float* __restrict__ Mh,
        float* __restrict__ cz, float* __restrict__ chv) {
    int b = blockIdx.x, t = threadIdx.x;
    if (b < 196) {
        int n = b * 256 + t;
        if (n < NN) dinv[n] = rsqrtf(deg[n] + 1.0f);   // +1 = self-loop
    } else if (b == 196) {
        __shared__ unsigned ts[256];
        unsigned v[4], s = 0;
#pragma unroll
        for (int r = 0; r < 4; ++r) {
            int idx = t * 4 + r;
            v[r] = (idx < NBIN) ? gbincnt[idx] : 0u;
            s += v[r];
        }
        ts[t] = s;
        __syncthreads();
        for (int off = 1; off < 256; off <<= 1) {
            unsigned u = (t >= off) ? ts[t - off] : 0u;
            __syncthreads();
            ts[t] += u;
            __syncthreads();
        }
        unsigned acc = (t > 0) ? ts[t - 1] : 0u;
#pragma unroll
        for (int r = 0; r < 4; ++r) {
            int idx = t * 4 + r;
            if (idx < NBIN) { binstart[idx] = acc; bincur[idx] = acc; }
            acc += v[r];
        }
        if (t == 255) binstart[NBIN] = NE;
    } else {
#pragma unroll
        for (int r = 0; r < 4; ++r) {
            int t2 = r * 256 + t;
            int i = t2 >> 5, j = t2 & 31;
            float sz = 0.f, sh = 0.f;
            for (int k = 0; k < 32; ++k) {
                sz += Wz[i * 32 + k] * Lzw[k * 32 + j];
                sh += Wh[i * 32 + k] * Lhw[k * 32 + j];
            }
            Mz[t2] = sz;
            Mh[t2] = sh;
        }
        if (t < 32) {
            float az = Lzb[t], ah = Lhb[t];
            for (int k = 0; k < 32; ++k) {
                az += bz[k] * Lzw[k * 32 + t];
                ah += bh[k] * Lhw[k * 32 + t];
            }
            cz[t] = az;
            chv[t] = ah;
        }
    }
}

// Bin edges by dst: per-block LDS count -> one coalesced global reservation
// per block (block-contiguous er ranges -> full-line L2 write-back) -> write
// records {src | dst_local<<16, dinv_s*ew*dinv_d}.
__global__ __launch_bounds__(512) void k_binwrite(const int* __restrict__ ei,
                                                  const float* __restrict__ ew,
                                                  const float* __restrict__ dinv,
                                                  unsigned* __restrict__ bincur,
                                                  float2* __restrict__ er) {
    __shared__ unsigned cnt[NBIN], base[NBIN];
    int t = threadIdx.x;
    for (int i = t; i < NBIN; i += 512) cnt[i] = 0u;
    __syncthreads();
    int lo = blockIdx.x * EPB, hi = lo + EPB;
    for (int e = lo + t; e < hi; e += 512)
        atomicAdd(&cnt[ei[NE + e] >> 6], 1u);              // LDS
    __syncthreads();
    for (int i = t; i < NBIN; i += 512)
        base[i] = atomicAdd(&bincur[i], cnt[i]);           // coalesced global
    __syncthreads();
    for (int e = lo + t; e < hi; e += 512) {
        int s = ei[e], d = ei[NE + e];
        float v = dinv[s] * ew[e] * dinv[d];
        unsigned idx = atomicAdd(&base[d >> 6], 1u);       // LDS cursor
        er[idx] = make_float2(
            __uint_as_float((unsigned)s | ((unsigned)(d & 63) << 16)), v);
    }
}

// One block per bin: LDS fp32 accumulator A[64][33] (padded), self-loop init,
// record accumulation (LDS atomics, <=2 lanes/bank), then the full dense
// epilogue in-block. A never touches global memory.
__global__ __launch_bounds__(512) void k_accum(
        const float2* __restrict__ er, const unsigned* __restrict__ binstart,
        const float* __restrict__ dinv, const float* __restrict__ x,
        const float* __restrict__ Mz, const float* __restrict__ Mh,
        const float* __restrict__ cz, const float* __restrict__ chv,
        const float* __restrict__ Wout, const float* __restrict__ bout,
        float* __restrict__ out) {
    __shared__ float A[NPB][33];
    __shared__ float sMz[1024], sMh[1024], sW[512], scz[32], sch[32], sb[16];
    int t = threadIdx.x;
    int node0 = blockIdx.x * NPB;
    for (int i = t; i < 1024; i += 512) { sMz[i] = Mz[i]; sMh[i] = Mh[i]; }
    sW[t] = Wout[t];
    if (t < 32) { scz[t] = cz[t]; sch[t] = chv[t]; }
    if (t < 16) sb[t] = bout[t];
    for (int i = t; i < NPB * 32; i += 512) {
        int l = i >> 5, f = i & 31, n = node0 + l;
        float a = 0.f;
        if (n < NN) { float dv = dinv[n]; a = dv * dv * x[n * 32 + f]; }
        A[l][f] = a;
    }
    __syncthreads();

    int f = t & 31, rid = t >> 5;   // 16 concurrent record slots
    unsigned beg = binstart[blockIdx.x], end = binstart[blockIdx.x + 1];
    for (unsigned i = beg + rid; i < end; i += 16) {
        float2 r = er[i];                         // 8B broadcast per half-wave
        unsigned pk = __float_as_uint(r.x);
        int src = pk & 0xFFFF, l = (pk >> 16) & 63;
        atomicAdd(&A[l][f], r.y * x[src * 32 + f]);  // LDS; x row = 128B gather
    }
    __syncthreads();

    float hreg[4];
#pragma unroll
    for (int r = 0; r < 4; ++r) {
        int g = rid + 16 * r;
        float z = scz[f], gh = sch[f];
#pragma unroll
        for (int k = 0; k < 32; ++k) {
            float ak = A[g][k];
            z += ak * sMz[k * 32 + f];
            gh += ak * sMh[k * 32 + f];
        }
        z = 1.0f / (1.0f + expf(-z));
        gh = tanhf(gh);
        float hv = (1.0f - z) * gh;     // H = (1-Z)*H_tilde  (Z*H0 = 0)
        hreg[r] = hv > 0.f ? hv : 0.f;  // relu fused
    }
    __syncthreads();
#pragma unroll
    for (int r = 0; r < 4; ++r) A[rid + 16 * r][f] = hreg[r];
    __syncthreads();

#pragma unroll
    for (int r = 0; r < 4; ++r) {
        int g = rid + 16 * r, n = node0 + g;
        if (f < 16 && n < NN) {           // uniform per 16-lane shfl partition
            float l = sb[f];
#pragma unroll
            for (int j = 0; j < 32; ++j) l += A[g][j] * sW[j * 16 + f];
            float mx = l;
#pragma unroll
            for (int w = 8; w >= 1; w >>= 1) mx = fmaxf(mx, __shfl_xor(mx, w, 16));
            float p = expf(l - mx);
            float sum = p;
#pragma unroll
            for (int w = 8; w >= 1; w >>= 1) sum += __shfl_xor(sum, w, 16);
            out[n * 16 + f] = p / sum;
        }
    }
}

extern "C" void kernel_launch(void* const* d_in, const int* in_sizes, int n_in,
                              void* d_out, int out_size, void* d_ws, size_t ws_size,
                              hipStream_t stream) {
    const float* x    = (const float*)d_in[0];
    const int*   ei   = (const int*)d_in[1];
    const float* ew   = (const float*)d_in[2];
    const float* Wz   = (const float*)d_in[3];
    const float* bz   = (const float*)d_in[4];
    // d_in[5..6] (Wr,br), d_in[11..12] (Lr): dead — R gate multiplies H0 = 0.
    const float* Wh   = (const float*)d_in[7];
    const float* bh   = (const float*)d_in[8];
    const float* Lzw  = (const float*)d_in[9];
    const float* Lzb  = (const float*)d_in[10];
    const float* Lhw  = (const float*)d_in[13];
    const float* Lhb  = (const float*)d_in[14];
    const float* Wout = (const float*)d_in[15];
    const float* bout = (const float*)d_in[16];
    float* out = (float*)d_out;

    float* ws = (float*)d_ws;
    float2*   er       = (float2*)ws;                        // 2*NE floats
    float*    deg      = ws + 2 * (size_t)NE;                // NN
    unsigned* gbincnt  = (unsigned*)(deg + NN);              // NBIN
    float*    dinv     = (float*)(gbincnt + NBIN);           // NN
    unsigned* binstart = (unsigned*)(dinv + NN);             // NBIN+1
    unsigned* bincur   = binstart + NBIN + 1;                // NBIN
    float*    Mz       = (float*)(bincur + NBIN);            // 1024
    float*    Mh       = Mz + 1024;
    float*    cz       = Mh + 1024;
    float*    chv      = cz + 32;

    hipMemsetAsync(deg, 0, (NN + NBIN) * sizeof(float), stream);

    k_deghist<<<2 * NBH, 1024, 0, stream>>>(ei, ew, deg, gbincnt);
    k_mid<<<198, 256, 0, stream>>>(deg, dinv, gbincnt, binstart, bincur,
                                   Wz, Lzw, bz, Lzb, Wh, Lhw, bh, Lhb,
                                   Mz, Mh, cz, chv);
    k_binwrite<<<WBLK, 512, 0, stream>>>(ei, ew, dinv, bincur, er);
    k_accum<<<NBIN, 512, 0, stream>>>(er, binstart, dinv, x, Mz, Mh, cz, chv,
                                      Wout, bout, out);
}

// Round 6
// 411.660 us; speedup vs baseline: 1.2008x; 1.2008x over previous
//
#include <hip/hip_runtime.h>

#define NN 50000
#define NE 1600000
#define NPB 32                       // nodes per bin
#define NBIN ((NN + NPB - 1) / NPB)  // 1563 (last bin: 16 valid nodes)
#define WBLK 256                     // edge-chunk blocks (cnt / binwrite)
#define EPB (NE / WBLK)              // 6250 edges per chunk

// ---------------- workspace layout ----------------
// er[NE] float2 {src|(l<<16), ew}  12.8 MB   (grouped by dst bin)
// Aout[NN*32] f32                   6.4 MB
// dinv[NN] | gbincnt[NBIN] (memset) | binstart[NBIN+1] | bincur[NBIN]
// Mz[1024] | Mh[1024] | cz[32] | ch[32]

// Per-bin edge counts: LDS histogram per chunk, dense coalesced flush.
__global__ __launch_bounds__(256) void k_cnt(const int* __restrict__ ei,
                                             unsigned* __restrict__ gbincnt) {
    __shared__ unsigned cnt[NBIN];
    int t = threadIdx.x;
    for (int i = t; i < NBIN; i += 256) cnt[i] = 0u;
    __syncthreads();
    int lo = blockIdx.x * EPB, hi = lo + EPB;
    for (int e = lo + t; e < hi; e += 256)
        atomicAdd(&cnt[ei[NE + e] >> 5], 1u);              // LDS
    __syncthreads();
    for (int i = t; i < NBIN; i += 256)
        if (cnt[i]) atomicAdd(&gbincnt[i], cnt[i]);        // dense coalesced
}

// b==0: exclusive scan of bin counts -> binstart/bincur.
// b==1: fold weights: Mz = Wz@Lzw[:32,:], cz = bz@Lzw + Lzb; same for h.
__global__ __launch_bounds__(256) void k_mid(
        const unsigned* __restrict__ gbincnt, unsigned* __restrict__ binstart,
        unsigned* __restrict__ bincur,
        const float* __restrict__ Wz, const float* __restrict__ Lzw,
        const float* __restrict__ bz, const float* __restrict__ Lzb,
        const float* __restrict__ Wh, const float* __restrict__ Lhw,
        const float* __restrict__ bh, const float* __restrict__ Lhb,
        float* __restrict__ Mz, float* __restrict__ Mh,
        float* __restrict__ cz, float* __restrict__ chv) {
    int t = threadIdx.x;
    if (blockIdx.x == 0) {
        __shared__ unsigned ts[256];
        unsigned v[7], s = 0;
#pragma unroll
        for (int r = 0; r < 7; ++r) {
            int idx = t * 7 + r;
            v[r] = (idx < NBIN) ? gbincnt[idx] : 0u;
            s += v[r];
        }
        ts[t] = s;
        __syncthreads();
        for (int off = 1; off < 256; off <<= 1) {
            unsigned u = (t >= off) ? ts[t - off] : 0u;
            __syncthreads();
            ts[t] += u;
            __syncthreads();
        }
        unsigned acc = (t > 0) ? ts[t - 1] : 0u;
#pragma unroll
        for (int r = 0; r < 7; ++r) {
            int idx = t * 7 + r;
            if (idx < NBIN) { binstart[idx] = acc; bincur[idx] = acc; }
            acc += v[r];
        }
        if (t == 0) binstart[NBIN] = NE;
    } else {
#pragma unroll
        for (int r = 0; r < 4; ++r) {
            int t2 = r * 256 + t;
            int i = t2 >> 5, j = t2 & 31;
            float sz = 0.f, sh = 0.f;
            for (int k = 0; k < 32; ++k) {
                sz += Wz[i * 32 + k] * Lzw[k * 32 + j];
                sh += Wh[i * 32 + k] * Lhw[k * 32 + j];
            }
            Mz[t2] = sz;
            Mh[t2] = sh;
        }
        if (t < 32) {
            float az = Lzb[t], ah = Lhb[t];
            for (int k = 0; k < 32; ++k) {
                az += bz[k] * Lzw[k * 32 + t];
                ah += bh[k] * Lhw[k * 32 + t];
            }
            cz[t] = az;
            chv[t] = ah;
        }
    }
}

// Bin edges by dst: LDS count -> one coalesced reservation per (block,bin) ->
// write raw records {src | dst_local<<16, ew}. Block-contiguous er ranges.
__global__ __launch_bounds__(512) void k_binwrite(const int* __restrict__ ei,
                                                  const float* __restrict__ ew,
                                                  unsigned* __restrict__ bincur,
                                                  float2* __restrict__ er) {
    __shared__ unsigned cnt[NBIN], base[NBIN];
    int t = threadIdx.x;
    for (int i = t; i < NBIN; i += 512) cnt[i] = 0u;
    __syncthreads();
    int lo = blockIdx.x * EPB, hi = lo + EPB;
    for (int e = lo + t; e < hi; e += 512)
        atomicAdd(&cnt[ei[NE + e] >> 5], 1u);              // LDS
    __syncthreads();
    for (int i = t; i < NBIN; i += 512)
        base[i] = cnt[i] ? atomicAdd(&bincur[i], cnt[i]) : 0u;  // coalesced
    __syncthreads();
    for (int e = lo + t; e < hi; e += 512) {
        int s = ei[e], d = ei[NE + e];
        unsigned idx = atomicAdd(&base[d >> 5], 1u);       // LDS cursor
        er[idx] = make_float2(
            __uint_as_float((unsigned)s | ((unsigned)(d & 31) << 16)), ew[e]);
    }
}

// Per-bin degree from the binned records themselves -> dinv (dense write).
__global__ __launch_bounds__(256) void k_deg(const float2* __restrict__ er,
                                             const unsigned* __restrict__ binstart,
                                             float* __restrict__ dinv) {
    __shared__ float degL[NPB];
    int t = threadIdx.x;
    if (t < NPB) degL[t] = 0.f;
    __syncthreads();
    unsigned beg = binstart[blockIdx.x], end = binstart[blockIdx.x + 1];
    for (unsigned i = beg + t; i < end; i += 256) {
        float2 r = er[i];
        atomicAdd(&degL[(__float_as_uint(r.x) >> 16) & 31u], r.y);  // LDS
    }
    __syncthreads();
    if (t < NPB) {
        int n = blockIdx.x * NPB + t;
        if (n < NN) dinv[n] = rsqrtf(degL[t] + 1.0f);  // +1 = self-loop
    }
}

// Gather: one block per bin, LDS fp32 accumulator A[32][33]. 32 record slots
// of 16 lanes (float2 features). A = dinv_d*(sum dinv_s*ew*x_s + dinv_d*x_d).
__global__ __launch_bounds__(512, 8) void k_accum(
        const float2* __restrict__ er, const unsigned* __restrict__ binstart,
        const float* __restrict__ dinv, const float* __restrict__ x,
        float* __restrict__ Aout) {
    __shared__ float A[NPB][33];
    __shared__ float sdv[NPB];
    const float2* x2 = (const float2*)x;
    int t = threadIdx.x;
    int l = t >> 4, j = t & 15;
    int node0 = blockIdx.x * NPB;
    int n = node0 + l;
    float dv = (n < NN) ? dinv[n] : 0.f;
    if (j == 0) sdv[l] = dv;
    float2 xv = (n < NN) ? x2[n * 16 + j] : make_float2(0.f, 0.f);
    A[l][2 * j]     = dv * xv.x;   // init = dinv_d * x_d (self-loop term)
    A[l][2 * j + 1] = dv * xv.y;
    __syncthreads();

    unsigned beg = binstart[blockIdx.x], end = binstart[blockIdx.x + 1];
    for (unsigned i = beg + (unsigned)l; i < end; i += 32) {
        float2 r = er[i];                         // 8B broadcast per 16 lanes
        unsigned pk = __float_as_uint(r.x);
        unsigned src = pk & 0xFFFFu;
        unsigned dl = (pk >> 16) & 31u;
        float v = r.y * dinv[src];                // L2-hot broadcast load
        float2 xs = x2[src * 16 + j];             // coalesced 128B row
        atomicAdd(&A[dl][2 * j], v * xs.x);       // LDS
        atomicAdd(&A[dl][2 * j + 1], v * xs.y);
    }
    __syncthreads();

    if (n < NN) {
        float2* o2 = (float2*)(Aout + (size_t)n * 32);
        o2[j] = make_float2(sdv[l] * A[l][2 * j], sdv[l] * A[l][2 * j + 1]);
    }
}

// Dense epilogue (proven r3 structure): gates + relu + 32x16 + softmax16.
__global__ __launch_bounds__(256) void k_dense(
        const float* __restrict__ Aout, const float* __restrict__ Mz,
        const float* __restrict__ Mh, const float* __restrict__ cz,
        const float* __restrict__ chv, const float* __restrict__ Wout,
        const float* __restrict__ bout, float* __restrict__ out) {
    __shared__ float sMz[1024], sMh[1024], sW[512], scz[32], sch[32], sb[16];
    __shared__ float sA[8][32];
    int tid = threadIdx.x;
    for (int i = tid; i < 1024; i += 256) { sMz[i] = Mz[i]; sMh[i] = Mh[i]; }
    for (int i = tid; i < 512; i += 256) sW[i] = Wout[i];
    if (tid < 32) { scz[tid] = cz[tid]; sch[tid] = chv[tid]; }
    if (tid < 16) sb[tid] = bout[tid];

    int g = tid >> 5, f = tid & 31;
    int n = blockIdx.x * 8 + g;
    float av = Aout[(size_t)n * 32 + f];
    sA[g][f] = av;
    __syncthreads();

    float z = scz[f], gh = sch[f];
#pragma unroll
    for (int k = 0; k < 32; ++k) {
        float ak = sA[g][k];
        z += ak * sMz[k * 32 + f];
        gh += ak * sMh[k * 32 + f];
    }
    z = 1.0f / (1.0f + expf(-z));
    gh = tanhf(gh);
    float hv = (1.0f - z) * gh;      // H = (1-Z)*H_tilde  (Z*H0 = 0)
    hv = hv > 0.f ? hv : 0.f;        // relu fused
    __syncthreads();
    sA[g][f] = hv;
    __syncthreads();

    if (f < 16) {
        float lg = sb[f];
#pragma unroll
        for (int j = 0; j < 32; ++j) lg += sA[g][j] * sW[j * 16 + f];
        float mx = lg;
#pragma unroll
        for (int w = 8; w >= 1; w >>= 1) mx = fmaxf(mx, __shfl_xor(mx, w, 16));
        float p = expf(lg - mx);
        float sum = p;
#pragma unroll
        for (int w = 8; w >= 1; w >>= 1) sum += __shfl_xor(sum, w, 16);
        out[n * 16 + f] = p / sum;
    }
}

extern "C" void kernel_launch(void* const* d_in, const int* in_sizes, int n_in,
                              void* d_out, int out_size, void* d_ws, size_t ws_size,
                              hipStream_t stream) {
    const float* x    = (const float*)d_in[0];
    const int*   ei   = (const int*)d_in[1];
    const float* ew   = (const float*)d_in[2];
    const float* Wz   = (const float*)d_in[3];
    const float* bz   = (const float*)d_in[4];
    // d_in[5..6] (Wr,br), d_in[11..12] (Lr): dead — R gate multiplies H0 = 0.
    const float* Wh   = (const float*)d_in[7];
    const float* bh   = (const float*)d_in[8];
    const float* Lzw  = (const float*)d_in[9];
    const float* Lzb  = (const float*)d_in[10];
    const float* Lhw  = (const float*)d_in[13];
    const float* Lhb  = (const float*)d_in[14];
    const float* Wout = (const float*)d_in[15];
    const float* bout = (const float*)d_in[16];
    float* out = (float*)d_out;

    float* ws = (float*)d_ws;
    float2*   er       = (float2*)ws;                        // NE float2
    float*    Aout     = ws + 2 * (size_t)NE;                // NN*32
    float*    dinv     = Aout + (size_t)NN * 32;             // NN
    unsigned* gbincnt  = (unsigned*)(dinv + NN);             // NBIN (memset)
    unsigned* binstart = gbincnt + NBIN;                     // NBIN+1
    unsigned* bincur   = binstart + NBIN + 1;                // NBIN
    float*    Mz       = (float*)(bincur + NBIN);            // 1024
    float*    Mh       = Mz + 1024;
    float*    cz       = Mh + 1024;
    float*    chv      = cz + 32;

    hipMemsetAsync(gbincnt, 0, NBIN * sizeof(unsigned), stream);

    k_cnt<<<WBLK, 256, 0, stream>>>(ei, gbincnt);
    k_mid<<<2, 256, 0, stream>>>(gbincnt, binstart, bincur,
                                 Wz, Lzw, bz, Lzb, Wh, Lhw, bh, Lhb,
                                 Mz, Mh, cz, chv);
    k_binwrite<<<WBLK, 512, 0, stream>>>(ei, ew, bincur, er);
    k_deg<<<NBIN, 256, 0, stream>>>(er, binstart, dinv);
    k_accum<<<NBIN, 512, 0, stream>>>(er, binstart, dinv, x, Aout);
    k_dense<<<NN / 8, 256, 0, stream>>>(Aout, Mz, Mh, cz, chv, Wout, bout, out);
}

// Round 7
// 151.746 us; speedup vs baseline: 3.2576x; 2.7128x over previous
//
#include <hip/hip_runtime.h>

#define NN 50000
#define NE 1600000
#define NPB 32                       // nodes per bin
#define NBIN ((NN + NPB - 1) / NPB)  // 1563 (last bin: 16 valid nodes)
#define NBH 128                      // deghist edge chunks
#define CHE (NE / NBH)               // 12500 edges/chunk
#define HALF 25000                   // nodes per deg-histogram half
#define WBLK 256                     // binwrite chunk blocks
#define EPB (NE / WBLK)              // 6250 edges/chunk
#define CAP 2048                     // staged records per bin (mean 1024, max ~1170)

// ---------------- workspace layout ----------------
// er[NE] float2 {src|(dl<<16), dinv_s*ew} grouped by dst-bin   12.8 MB
// Aout[NN*32] f32   6.4 MB
// deg[NN] | gbincnt[NBIN]  (contiguous, memset 0)
// dinv[NN] | binstart[NBIN+1] | bincur[NBIN] | Mz[1024] | Mh[1024] | cz[32] | ch[32]

// deg via LDS weight-histogram (2 halves x 128 chunks); p==0 blocks also count
// edges per dst-bin. All global atomics are dense coalesced flushes.
__global__ __launch_bounds__(1024) void k_deghist(const int* __restrict__ ei,
                                                  const float* __restrict__ ew,
                                                  float* __restrict__ deg,
                                                  unsigned* __restrict__ gbincnt) {
    __shared__ float hist[HALF];     // 100 KB
    __shared__ unsigned bcnt[NBIN];  // 6.3 KB
    int p = blockIdx.x >> 7;
    int c = blockIdx.x & 127;
    int base = p * HALF;
    for (int i = threadIdx.x; i < HALF; i += 1024) hist[i] = 0.f;
    if (p == 0)
        for (int i = threadIdx.x; i < NBIN; i += 1024) bcnt[i] = 0u;
    __syncthreads();
    int lo = c * CHE, hi = lo + CHE;
    for (int e = lo + threadIdx.x; e < hi; e += 1024) {
        int d = ei[NE + e];
        if (p == 0) atomicAdd(&bcnt[d >> 5], 1u);          // LDS, rare collision
        unsigned r = (unsigned)(d - base);
        if (r < HALF) atomicAdd(&hist[r], ew[e]);          // LDS, rare collision
    }
    __syncthreads();
    for (int i = threadIdx.x; i < HALF; i += 1024)
        atomicAdd(&deg[base + i], hist[i]);                // dense coalesced
    if (p == 0)
        for (int i = threadIdx.x; i < NBIN; i += 1024)
            if (bcnt[i]) atomicAdd(&gbincnt[i], bcnt[i]);  // dense coalesced
}

// b==0: exclusive scan of bin counts. b==1: fold weights (H0=0 kills R gate +
// bottom gate halves). b>=2: dinv = rsqrt(deg+1).
__global__ __launch_bounds__(256) void k_mid(
        const float* __restrict__ deg, float* __restrict__ dinv,
        const unsigned* __restrict__ gbincnt, unsigned* __restrict__ binstart,
        unsigned* __restrict__ bincur,
        const float* __restrict__ Wz, const float* __restrict__ Lzw,
        const float* __restrict__ bz, const float* __restrict__ Lzb,
        const float* __restrict__ Wh, const float* __restrict__ Lhw,
        const float* __restrict__ bh, const float* __restrict__ Lhb,
        float* __restrict__ Mz, float* __restrict__ Mh,
        float* __restrict__ cz, float* __restrict__ chv) {
    int t = threadIdx.x, b = blockIdx.x;
    if (b == 0) {
        __shared__ unsigned ts[256];
        unsigned v[7], s = 0;
#pragma unroll
        for (int r = 0; r < 7; ++r) {
            int idx = t * 7 + r;
            v[r] = (idx < NBIN) ? gbincnt[idx] : 0u;
            s += v[r];
        }
        ts[t] = s;
        __syncthreads();
        for (int off = 1; off < 256; off <<= 1) {
            unsigned u = (t >= off) ? ts[t - off] : 0u;
            __syncthreads();
            ts[t] += u;
            __syncthreads();
        }
        unsigned acc = (t > 0) ? ts[t - 1] : 0u;
#pragma unroll
        for (int r = 0; r < 7; ++r) {
            int idx = t * 7 + r;
            if (idx < NBIN) { binstart[idx] = acc; bincur[idx] = acc; }
            acc += v[r];
        }
        if (t == 0) binstart[NBIN] = NE;
    } else if (b == 1) {
#pragma unroll
        for (int r = 0; r < 4; ++r) {
            int t2 = r * 256 + t;
            int i = t2 >> 5, j = t2 & 31;
            float sz = 0.f, sh = 0.f;
            for (int k = 0; k < 32; ++k) {
                sz += Wz[i * 32 + k] * Lzw[k * 32 + j];
                sh += Wh[i * 32 + k] * Lhw[k * 32 + j];
            }
            Mz[t2] = sz;
            Mh[t2] = sh;
        }
        if (t < 32) {
            float az = Lzb[t], ah = Lhb[t];
            for (int k = 0; k < 32; ++k) {
                az += bz[k] * Lzw[k * 32 + t];
                ah += bh[k] * Lhw[k * 32 + t];
            }
            cz[t] = az;
            chv[t] = ah;
        }
    } else {
        int n = (b - 2) * 256 + t;
        if (n < NN) dinv[n] = rsqrtf(deg[n] + 1.0f);   // +1 = self-loop
    }
}

// Bin edges by dst: LDS count -> one coalesced reservation per (block,bin) ->
// write records {src | dst_local<<16, dinv_s*ew}. Block-contiguous er ranges.
__global__ __launch_bounds__(512) void k_binwrite(const int* __restrict__ ei,
                                                  const float* __restrict__ ew,
                                                  const float* __restrict__ dinv,
                                                  unsigned* __restrict__ bincur,
                                                  float2* __restrict__ er) {
    __shared__ unsigned cnt[NBIN], base[NBIN];
    int t = threadIdx.x;
    for (int i = t; i < NBIN; i += 512) cnt[i] = 0u;
    __syncthreads();
    int lo = blockIdx.x * EPB, hi = lo + EPB;
    for (int e = lo + t; e < hi; e += 512)
        atomicAdd(&cnt[ei[NE + e] >> 5], 1u);              // LDS
    __syncthreads();
    for (int i = t; i < NBIN; i += 512)
        base[i] = cnt[i] ? atomicAdd(&bincur[i], cnt[i]) : 0u;  // coalesced
    __syncthreads();
    for (int e = lo + t; e < hi; e += 512) {
        int s = ei[e], d = ei[NE + e];
        float v = dinv[s] * ew[e];                          // premultiplied
        unsigned idx = atomicAdd(&base[d >> 5], 1u);        // LDS cursor
        er[idx] = make_float2(
            __uint_as_float((unsigned)s | ((unsigned)(d & 31) << 16)), v);
    }
}

// One block (256 thr) per bin. Stage records in regs -> per-wave hist -> shfl
// scan -> scatter to SORTED LDS -> owner-computes register accumulation
// (no atomics on the accumulator). Thread (l = t>>3, j = t&7) owns node l's
// float4 feature slice. All 1563 blocks co-resident (18KB LDS, 8 blocks/CU).
__global__ __launch_bounds__(256) void k_accum(
        const float2* __restrict__ er, const unsigned* __restrict__ binstart,
        const float* __restrict__ dinv, const float* __restrict__ x,
        float* __restrict__ Aout) {
    __shared__ float2 srt[CAP];          // 16 KB
    __shared__ unsigned cnt4[4][32];     // per-wave hist
    __shared__ unsigned base4[4][32];    // scatter cursors
    __shared__ unsigned rowp[33];
    const float4* x4 = (const float4*)x;
    int t = threadIdx.x;
    int w = t >> 6;
    unsigned beg = binstart[blockIdx.x], end = binstart[blockIdx.x + 1];
    unsigned cntb = end - beg;
    unsigned stage = cntb < CAP ? cntb : CAP;

    if (t < 128) ((unsigned*)cnt4)[t] = 0u;
    __syncthreads();

    // stage up to 8 records/thread + per-wave histogram (static indices only)
    float2 rec[8];
    unsigned dlk[8];
    bool val[8];
#pragma unroll
    for (int k = 0; k < 8; ++k) {
        unsigned i = (unsigned)t + (unsigned)k * 256u;
        val[k] = (i < stage);
        if (val[k]) {
            float2 r = er[beg + i];
            rec[k] = r;
            unsigned d = (__float_as_uint(r.x) >> 16) & 31u;
            dlk[k] = d;
            atomicAdd(&cnt4[w][d], 1u);   // within-wave collisions only
        }
    }
    __syncthreads();

    // lanes 0..31 of wave 0: per-node totals, exclusive scan, per-wave bases
    if (t < 32) {
        unsigned s = 0;
#pragma unroll
        for (int ww = 0; ww < 4; ++ww) {
            unsigned c = cnt4[ww][t];
            base4[ww][t] = s;
            s += c;
        }
        unsigned tot = s;
#pragma unroll
        for (int off = 1; off < 32; off <<= 1) {
            unsigned v = __shfl_up(tot, off, 32);
            if (t >= off) tot += v;
        }
        unsigned excl = tot - s;
        rowp[t] = excl;
        if (t == 31) rowp[32] = excl + s;
#pragma unroll
        for (int ww = 0; ww < 4; ++ww) base4[ww][t] += excl;
    }
    __syncthreads();

    // scatter to sorted LDS
#pragma unroll
    for (int k = 0; k < 8; ++k) {
        if (val[k]) {
            unsigned p = atomicAdd(&base4[w][dlk[k]], 1u);
            srt[p] = rec[k];
        }
    }
    __syncthreads();

    // owner-computes: node l, float4 slice j. Register accumulation.
    int l = t >> 3, j = t & 7;
    int n = blockIdx.x * NPB + l;
    float4 acc = make_float4(0.f, 0.f, 0.f, 0.f);
    unsigned rb = rowp[l], re = rowp[l + 1];
    unsigned i = rb;
    for (; i + 4 <= re; i += 4) {
        float2 r0 = srt[i], r1 = srt[i + 1], r2 = srt[i + 2], r3 = srt[i + 3];
        unsigned s0 = __float_as_uint(r0.x) & 0xFFFFu;
        unsigned s1 = __float_as_uint(r1.x) & 0xFFFFu;
        unsigned s2 = __float_as_uint(r2.x) & 0xFFFFu;
        unsigned s3 = __float_as_uint(r3.x) & 0xFFFFu;
        float4 a0 = x4[s0 * 8 + j];
        float4 a1 = x4[s1 * 8 + j];
        float4 a2 = x4[s2 * 8 + j];
        float4 a3 = x4[s3 * 8 + j];
        acc.x += r0.y * a0.x; acc.y += r0.y * a0.y; acc.z += r0.y * a0.z; acc.w += r0.y * a0.w;
        acc.x += r1.y * a1.x; acc.y += r1.y * a1.y; acc.z += r1.y * a1.z; acc.w += r1.y * a1.w;
        acc.x += r2.y * a2.x; acc.y += r2.y * a2.y; acc.z += r2.y * a2.z; acc.w += r2.y * a2.w;
        acc.x += r3.y * a3.x; acc.y += r3.y * a3.y; acc.z += r3.y * a3.z; acc.w += r3.y * a3.w;
    }
    for (; i < re; ++i) {
        float2 r = srt[i];
        unsigned s = __float_as_uint(r.x) & 0xFFFFu;
        float4 a = x4[s * 8 + j];
        acc.x += r.y * a.x; acc.y += r.y * a.y; acc.z += r.y * a.z; acc.w += r.y * a.w;
    }
    // overflow fallback (never triggers for this input: max bin ~1170 < 2048)
    for (unsigned o = stage; o < cntb; ++o) {
        float2 r = er[beg + o];
        unsigned pk = __float_as_uint(r.x);
        if (((pk >> 16) & 31u) == (unsigned)l) {
            float4 a = x4[(pk & 0xFFFFu) * 8 + j];
            acc.x += r.y * a.x; acc.y += r.y * a.y; acc.z += r.y * a.z; acc.w += r.y * a.w;
        }
    }
    if (n < NN) {
        float dv = dinv[n];
        float4 xv = x4[n * 8 + j];
        float4 o;
        o.x = dv * (acc.x + dv * xv.x);
        o.y = dv * (acc.y + dv * xv.y);
        o.z = dv * (acc.z + dv * xv.z);
        o.w = dv * (acc.w + dv * xv.w);
        ((float4*)Aout)[n * 8 + j] = o;
    }
}

// Dense epilogue: gates + relu + 32x16 matvec + softmax16. 32 lanes = 1 node.
__global__ __launch_bounds__(256) void k_dense(
        const float* __restrict__ Aout, const float* __restrict__ Mz,
        const float* __restrict__ Mh, const float* __restrict__ cz,
        const float* __restrict__ chv, const float* __restrict__ Wout,
        const float* __restrict__ bout, float* __restrict__ out) {
    __shared__ float sMz[1024], sMh[1024], sW[512], scz[32], sch[32], sb[16];
    __shared__ float sA[8][32];
    int tid = threadIdx.x;
    for (int i = tid; i < 1024; i += 256) { sMz[i] = Mz[i]; sMh[i] = Mh[i]; }
    for (int i = tid; i < 512; i += 256) sW[i] = Wout[i];
    if (tid < 32) { scz[tid] = cz[tid]; sch[tid] = chv[tid]; }
    if (tid < 16) sb[tid] = bout[tid];

    int g = tid >> 5, f = tid & 31;
    int n = blockIdx.x * 8 + g;
    float av = Aout[(size_t)n * 32 + f];
    sA[g][f] = av;
    __syncthreads();

    float z = scz[f], gh = sch[f];
#pragma unroll
    for (int k = 0; k < 32; ++k) {
        float ak = sA[g][k];
        z += ak * sMz[k * 32 + f];
        gh += ak * sMh[k * 32 + f];
    }
    z = 1.0f / (1.0f + expf(-z));
    gh = tanhf(gh);
    float hv = (1.0f - z) * gh;      // H = (1-Z)*H_tilde  (Z*H0 = 0)
    hv = hv > 0.f ? hv : 0.f;        // relu fused
    __syncthreads();
    sA[g][f] = hv;
    __syncthreads();

    if (f < 16) {
        float lg = sb[f];
#pragma unroll
        for (int j = 0; j < 32; ++j) lg += sA[g][j] * sW[j * 16 + f];
        float mx = lg;
#pragma unroll
        for (int w = 8; w >= 1; w >>= 1) mx = fmaxf(mx, __shfl_xor(mx, w, 16));
        float p = expf(lg - mx);
        float sum = p;
#pragma unroll
        for (int w = 8; w >= 1; w >>= 1) sum += __shfl_xor(sum, w, 16);
        out[n * 16 + f] = p / sum;
    }
}

extern "C" void kernel_launch(void* const* d_in, const int* in_sizes, int n_in,
                              void* d_out, int out_size, void* d_ws, size_t ws_size,
                              hipStream_t stream) {
    const float* x    = (const float*)d_in[0];
    const int*   ei   = (const int*)d_in[1];
    const float* ew   = (const float*)d_in[2];
    const float* Wz   = (const float*)d_in[3];
    const float* bz   = (const float*)d_in[4];
    // d_in[5..6] (Wr,br), d_in[11..12] (Lr): dead — R gate multiplies H0 = 0.
    const float* Wh   = (const float*)d_in[7];
    const float* bh   = (const float*)d_in[8];
    const float* Lzw  = (const float*)d_in[9];
    const float* Lzb  = (const float*)d_in[10];
    const float* Lhw  = (const float*)d_in[13];
    const float* Lhb  = (const float*)d_in[14];
    const float* Wout = (const float*)d_in[15];
    const float* bout = (const float*)d_in[16];
    float* out = (float*)d_out;

    float* ws = (float*)d_ws;
    float2*   er       = (float2*)ws;                        // NE float2
    float*    Aout     = ws + 2 * (size_t)NE;                // NN*32
    float*    deg      = Aout + (size_t)NN * 32;             // NN   (memset)
    unsigned* gbincnt  = (unsigned*)(deg + NN);              // NBIN (memset)
    float*    dinv     = (float*)(gbincnt + NBIN);           // NN
    unsigned* binstart = (unsigned*)(dinv + NN);             // NBIN+1
    unsigned* bincur   = binstart + NBIN + 1;                // NBIN
    float*    Mz       = (float*)(bincur + NBIN);            // 1024
    float*    Mh       = Mz + 1024;
    float*    cz       = Mh + 1024;
    float*    chv      = cz + 32;

    hipMemsetAsync(deg, 0, (NN + NBIN) * sizeof(float), stream);

    k_deghist<<<2 * NBH, 1024, 0, stream>>>(ei, ew, deg, gbincnt);
    k_mid<<<2 + (NN + 255) / 256, 256, 0, stream>>>(deg, dinv, gbincnt, binstart,
                                                    bincur, Wz, Lzw, bz, Lzb,
                                                    Wh, Lhw, bh, Lhb, Mz, Mh, cz, chv);
    k_binwrite<<<WBLK, 512, 0, stream>>>(ei, ew, dinv, bincur, er);
    k_accum<<<NBIN, 256, 0, stream>>>(er, binstart, dinv, x, Aout);
    k_dense<<<NN / 8, 256, 0, stream>>>(Aout, Mz, Mh, cz, chv, Wout, bout, out);
}

// Round 8
// 123.585 us; speedup vs baseline: 4.0000x; 1.2279x over previous
//
#include <hip/hip_runtime.h>

#define NN 50000
#define NE 1600000
#define NPB 32                       // nodes per bin
#define NBIN ((NN + NPB - 1) / NPB)  // 1563 (last bin: 16 valid nodes)
#define NXCD 8
#define WBLK 512                     // cnt / binwrite chunk blocks
#define EPB (NE / WBLK)              // 3125 edges per chunk
#define CAP 2048                     // staged records per bin (mean 1024, max ~1170)

// ---------------- workspace layout ----------------
// er[NE] float2 {src|(dl<<16), ew}, ordered by (bin, xcd)        12.8 MB
// Aout[NN*32] f32                                                 6.4 MB
// dinv[NN]
// gbincnt8[8*NBIN] u32 (memset 0)  : per-(xcd,bin) record counts
// binstart[NBIN+1] u32             : per-bin global ranges
// bincur8[8*NBIN] u32              : per-(xcd,bin) write cursors
// Mz[1024] | Mh[1024] | cz[32] | ch[32]

// Per-(xcd,bin) edge counts: LDS histogram per chunk, dense coalesced flush
// into this block's XCD row.
__global__ __launch_bounds__(256) void k_cnt(const int* __restrict__ ei,
                                             unsigned* __restrict__ gbincnt8) {
    __shared__ unsigned cnt[NBIN];
    int t = threadIdx.x;
    int xcd = blockIdx.x & (NXCD - 1);
    for (int i = t; i < NBIN; i += 256) cnt[i] = 0u;
    __syncthreads();
    int lo = blockIdx.x * EPB, hi = lo + EPB;
    for (int e = lo + t; e < hi; e += 256)
        atomicAdd(&cnt[ei[NE + e] >> 5], 1u);              // LDS
    __syncthreads();
    for (int i = t; i < NBIN; i += 256)
        if (cnt[i]) atomicAdd(&gbincnt8[xcd * NBIN + i], cnt[i]);  // coalesced
}

// b==0: scan per-(xcd,bin) counts -> binstart (bin-contiguous) + bincur8
//       (xcd sub-offsets within each bin).
// b==1: fold weights: Mz = Wz@Lzw[:32,:], cz = bz@Lzw + Lzb; same for h.
//       (H0 = 0 kills the R gate and the bottom halves of the gate linears.)
__global__ __launch_bounds__(256) void k_mid(
        const unsigned* __restrict__ gbincnt8, unsigned* __restrict__ binstart,
        unsigned* __restrict__ bincur8,
        const float* __restrict__ Wz, const float* __restrict__ Lzw,
        const float* __restrict__ bz, const float* __restrict__ Lzb,
        const float* __restrict__ Wh, const float* __restrict__ Lhw,
        const float* __restrict__ bh, const float* __restrict__ Lhb,
        float* __restrict__ Mz, float* __restrict__ Mh,
        float* __restrict__ cz, float* __restrict__ chv) {
    int t = threadIdx.x;
    if (blockIdx.x == 0) {
        __shared__ unsigned ts[256];
        unsigned s = 0;
#pragma unroll
        for (int r = 0; r < 7; ++r) {
            int idx = t * 7 + r;
            if (idx < NBIN)
                for (int x = 0; x < NXCD; ++x) s += gbincnt8[x * NBIN + idx];
        }
        ts[t] = s;
        __syncthreads();
        for (int off = 1; off < 256; off <<= 1) {
            unsigned u = (t >= off) ? ts[t - off] : 0u;
            __syncthreads();
            ts[t] += u;
            __syncthreads();
        }
        unsigned acc = (t > 0) ? ts[t - 1] : 0u;
#pragma unroll
        for (int r = 0; r < 7; ++r) {
            int idx = t * 7 + r;
            if (idx < NBIN) {
                binstart[idx] = acc;
                for (int x = 0; x < NXCD; ++x) {
                    bincur8[x * NBIN + idx] = acc;
                    acc += gbincnt8[x * NBIN + idx];
                }
            }
        }
        if (t == 255) binstart[NBIN] = NE;
    } else {
#pragma unroll
        for (int r = 0; r < 4; ++r) {
            int t2 = r * 256 + t;
            int i = t2 >> 5, j = t2 & 31;
            float sz = 0.f, sh = 0.f;
            for (int k = 0; k < 32; ++k) {
                sz += Wz[i * 32 + k] * Lzw[k * 32 + j];
                sh += Wh[i * 32 + k] * Lhw[k * 32 + j];
            }
            Mz[t2] = sz;
            Mh[t2] = sh;
        }
        if (t < 32) {
            float az = Lzb[t], ah = Lhb[t];
            for (int k = 0; k < 32; ++k) {
                az += bz[k] * Lzw[k * 32 + t];
                ah += bh[k] * Lhw[k * 32 + t];
            }
            cz[t] = az;
            chv[t] = ah;
        }
    }
}

// Bin edges by dst into XCD-private sub-ranges: LDS count -> coalesced
// reservation on this XCD's cursor row -> scatter records {src|dl<<16, ew}.
// All stores to any er cache line come from ONE XCD -> full-line write-back.
__global__ __launch_bounds__(256) void k_binwrite(const int* __restrict__ ei,
                                                  const float* __restrict__ ew,
                                                  unsigned* __restrict__ bincur8,
                                                  float2* __restrict__ er) {
    __shared__ unsigned cnt[NBIN], base[NBIN];
    int t = threadIdx.x;
    int xcd = blockIdx.x & (NXCD - 1);
    for (int i = t; i < NBIN; i += 256) cnt[i] = 0u;
    __syncthreads();
    int lo = blockIdx.x * EPB, hi = lo + EPB;
    for (int e = lo + t; e < hi; e += 256)
        atomicAdd(&cnt[ei[NE + e] >> 5], 1u);              // LDS
    __syncthreads();
    for (int i = t; i < NBIN; i += 256)
        base[i] = cnt[i] ? atomicAdd(&bincur8[xcd * NBIN + i], cnt[i]) : 0u;
    __syncthreads();
    for (int e = lo + t; e < hi; e += 256) {
        int s = ei[e], d = ei[NE + e];
        unsigned idx = atomicAdd(&base[d >> 5], 1u);       // LDS cursor
        er[idx] = make_float2(
            __uint_as_float((unsigned)s | ((unsigned)(d & 31) << 16)), ew[e]);
    }
}

// Per-bin in-weight sums from the binned records -> dinv (dense write).
__global__ __launch_bounds__(256) void k_deg(const float2* __restrict__ er,
                                             const unsigned* __restrict__ binstart,
                                             float* __restrict__ dinv) {
    __shared__ float degL[NPB];
    int t = threadIdx.x;
    if (t < NPB) degL[t] = 0.f;
    __syncthreads();
    unsigned beg = binstart[blockIdx.x], end = binstart[blockIdx.x + 1];
    for (unsigned i = beg + t; i < end; i += 256) {
        float2 r = er[i];
        atomicAdd(&degL[(__float_as_uint(r.x) >> 16) & 31u], r.y);  // LDS
    }
    __syncthreads();
    if (t < NPB) {
        int n = blockIdx.x * NPB + t;
        if (n < NN) dinv[n] = rsqrtf(degL[t] + 1.0f);  // +1 = self-loop
    }
}

// One block (256 thr) per bin. Stage records in regs (x dinv[src]) -> per-wave
// hist -> shfl scan -> scatter to SORTED LDS -> owner-computes register
// accumulation (no accumulator atomics). Thread (l = t>>3, j = t&7) owns node
// l's float4 feature slice.
__global__ __launch_bounds__(256) void k_accum(
        const float2* __restrict__ er, const unsigned* __restrict__ binstart,
        const float* __restrict__ dinv, const float* __restrict__ x,
        float* __restrict__ Aout) {
    __shared__ float2 srt[CAP];          // 16 KB
    __shared__ unsigned cnt4[4][32];     // per-wave hist
    __shared__ unsigned base4[4][32];    // scatter cursors
    __shared__ unsigned rowp[33];
    const float4* x4 = (const float4*)x;
    int t = threadIdx.x;
    int w = t >> 6;
    unsigned beg = binstart[blockIdx.x], end = binstart[blockIdx.x + 1];
    unsigned cntb = end - beg;
    unsigned stage = cntb < CAP ? cntb : CAP;

    if (t < 128) ((unsigned*)cnt4)[t] = 0u;
    __syncthreads();

    // stage up to 8 records/thread (weight premultiplied by dinv[src]) + hist
    float2 rec[8];
    unsigned dlk[8];
    bool val[8];
#pragma unroll
    for (int k = 0; k < 8; ++k) {
        unsigned i = (unsigned)t + (unsigned)k * 256u;
        val[k] = (i < stage);
        if (val[k]) {
            float2 r = er[beg + i];
            unsigned pk = __float_as_uint(r.x);
            r.y *= dinv[pk & 0xFFFFu];            // L2-hot 200KB broadcast
            rec[k] = r;
            unsigned d = (pk >> 16) & 31u;
            dlk[k] = d;
            atomicAdd(&cnt4[w][d], 1u);           // within-wave collisions only
        }
    }
    __syncthreads();

    // lanes 0..31 of wave 0: per-node totals, exclusive scan, per-wave bases
    if (t < 32) {
        unsigned s = 0;
#pragma unroll
        for (int ww = 0; ww < 4; ++ww) {
            unsigned c = cnt4[ww][t];
            base4[ww][t] = s;
            s += c;
        }
        unsigned tot = s;
#pragma unroll
        for (int off = 1; off < 32; off <<= 1) {
            unsigned v = __shfl_up(tot, off, 32);
            if (t >= off) tot += v;
        }
        unsigned excl = tot - s;
        rowp[t] = excl;
        if (t == 31) rowp[32] = excl + s;
#pragma unroll
        for (int ww = 0; ww < 4; ++ww) base4[ww][t] += excl;
    }
    __syncthreads();

    // scatter to sorted LDS
#pragma unroll
    for (int k = 0; k < 8; ++k) {
        if (val[k]) {
            unsigned p = atomicAdd(&base4[w][dlk[k]], 1u);
            srt[p] = rec[k];
        }
    }
    __syncthreads();

    // owner-computes: node l, float4 slice j. Register accumulation.
    int l = t >> 3, j = t & 7;
    int n = blockIdx.x * NPB + l;
    float4 acc = make_float4(0.f, 0.f, 0.f, 0.f);
    unsigned rb = rowp[l], re = rowp[l + 1];
    unsigned i = rb;
    for (; i + 4 <= re; i += 4) {
        float2 r0 = srt[i], r1 = srt[i + 1], r2 = srt[i + 2], r3 = srt[i + 3];
        unsigned s0 = __float_as_uint(r0.x) & 0xFFFFu;
        unsigned s1 = __float_as_uint(r1.x) & 0xFFFFu;
        unsigned s2 = __float_as_uint(r2.x) & 0xFFFFu;
        unsigned s3 = __float_as_uint(r3.x) & 0xFFFFu;
        float4 a0 = x4[s0 * 8 + j];
        float4 a1 = x4[s1 * 8 + j];
        float4 a2 = x4[s2 * 8 + j];
        float4 a3 = x4[s3 * 8 + j];
        acc.x += r0.y * a0.x; acc.y += r0.y * a0.y; acc.z += r0.y * a0.z; acc.w += r0.y * a0.w;
        acc.x += r1.y * a1.x; acc.y += r1.y * a1.y; acc.z += r1.y * a1.z; acc.w += r1.y * a1.w;
        acc.x += r2.y * a2.x; acc.y += r2.y * a2.y; acc.z += r2.y * a2.z; acc.w += r2.y * a2.w;
        acc.x += r3.y * a3.x; acc.y += r3.y * a3.y; acc.z += r3.y * a3.z; acc.w += r3.y * a3.w;
    }
    for (; i < re; ++i) {
        float2 r = srt[i];
        unsigned s = __float_as_uint(r.x) & 0xFFFFu;
        float4 a = x4[s * 8 + j];
        acc.x += r.y * a.x; acc.y += r.y * a.y; acc.z += r.y * a.z; acc.w += r.y * a.w;
    }
    // overflow fallback (never triggers for this input: max bin ~1170 < 2048)
    for (unsigned o = stage; o < cntb; ++o) {
        float2 r = er[beg + o];
        unsigned pk = __float_as_uint(r.x);
        if (((pk >> 16) & 31u) == (unsigned)l) {
            unsigned s = pk & 0xFFFFu;
            float4 a = x4[s * 8 + j];
            float v = r.y * dinv[s];
            acc.x += v * a.x; acc.y += v * a.y; acc.z += v * a.z; acc.w += v * a.w;
        }
    }
    if (n < NN) {
        float dv = dinv[n];
        float4 xv = x4[n * 8 + j];
        float4 o;
        o.x = dv * (acc.x + dv * xv.x);
        o.y = dv * (acc.y + dv * xv.y);
        o.z = dv * (acc.z + dv * xv.z);
        o.w = dv * (acc.w + dv * xv.w);
        ((float4*)Aout)[n * 8 + j] = o;
    }
}

// Dense epilogue: gates + relu + 32x16 matvec + softmax16. 32 lanes = 1 node.
__global__ __launch_bounds__(256) void k_dense(
        const float* __restrict__ Aout, const float* __restrict__ Mz,
        const float* __restrict__ Mh, const float* __restrict__ cz,
        const float* __restrict__ chv, const float* __restrict__ Wout,
        const float* __restrict__ bout, float* __restrict__ out) {
    __shared__ float sMz[1024], sMh[1024], sW[512], scz[32], sch[32], sb[16];
    __shared__ float sA[8][32];
    int tid = threadIdx.x;
    for (int i = tid; i < 1024; i += 256) { sMz[i] = Mz[i]; sMh[i] = Mh[i]; }
    for (int i = tid; i < 512; i += 256) sW[i] = Wout[i];
    if (tid < 32) { scz[tid] = cz[tid]; sch[tid] = chv[tid]; }
    if (tid < 16) sb[tid] = bout[tid];

    int g = tid >> 5, f = tid & 31;
    int n = blockIdx.x * 8 + g;
    float av = Aout[(size_t)n * 32 + f];
    sA[g][f] = av;
    __syncthreads();

    float z = scz[f], gh = sch[f];
#pragma unroll
    for (int k = 0; k < 32; ++k) {
        float ak = sA[g][k];
        z += ak * sMz[k * 32 + f];
        gh += ak * sMh[k * 32 + f];
    }
    z = 1.0f / (1.0f + expf(-z));
    gh = tanhf(gh);
    float hv = (1.0f - z) * gh;      // H = (1-Z)*H_tilde  (Z*H0 = 0)
    hv = hv > 0.f ? hv : 0.f;        // relu fused
    __syncthreads();
    sA[g][f] = hv;
    __syncthreads();

    if (f < 16) {
        float lg = sb[f];
#pragma unroll
        for (int j = 0; j < 32; ++j) lg += sA[g][j] * sW[j * 16 + f];
        float mx = lg;
#pragma unroll
        for (int w = 8; w >= 1; w >>= 1) mx = fmaxf(mx, __shfl_xor(mx, w, 16));
        float p = expf(lg - mx);
        float sum = p;
#pragma unroll
        for (int w = 8; w >= 1; w >>= 1) sum += __shfl_xor(sum, w, 16);
        out[n * 16 + f] = p / sum;
    }
}

extern "C" void kernel_launch(void* const* d_in, const int* in_sizes, int n_in,
                              void* d_out, int out_size, void* d_ws, size_t ws_size,
                              hipStream_t stream) {
    const float* x    = (const float*)d_in[0];
    const int*   ei   = (const int*)d_in[1];
    const float* ew   = (const float*)d_in[2];
    const float* Wz   = (const float*)d_in[3];
    const float* bz   = (const float*)d_in[4];
    // d_in[5..6] (Wr,br), d_in[11..12] (Lr): dead — R gate multiplies H0 = 0.
    const float* Wh   = (const float*)d_in[7];
    const float* bh   = (const float*)d_in[8];
    const float* Lzw  = (const float*)d_in[9];
    const float* Lzb  = (const float*)d_in[10];
    const float* Lhw  = (const float*)d_in[13];
    const float* Lhb  = (const float*)d_in[14];
    const float* Wout = (const float*)d_in[15];
    const float* bout = (const float*)d_in[16];
    float* out = (float*)d_out;

    float* ws = (float*)d_ws;
    float2*   er       = (float2*)ws;                        // NE float2
    float*    Aout     = ws + 2 * (size_t)NE;                // NN*32
    float*    dinv     = Aout + (size_t)NN * 32;             // NN
    unsigned* gbincnt8 = (unsigned*)(dinv + NN);             // 8*NBIN (memset)
    unsigned* binstart = gbincnt8 + NXCD * NBIN;             // NBIN+1
    unsigned* bincur8  = binstart + NBIN + 1;                // 8*NBIN
    float*    Mz       = (float*)(bincur8 + NXCD * NBIN);    // 1024
    float*    Mh       = Mz + 1024;
    float*    cz       = Mh + 1024;
    float*    chv      = cz + 32;

    hipMemsetAsync(gbincnt8, 0, NXCD * NBIN * sizeof(unsigned), stream);

    k_cnt<<<WBLK, 256, 0, stream>>>(ei, gbincnt8);
    k_mid<<<2, 256, 0, stream>>>(gbincnt8, binstart, bincur8,
                                 Wz, Lzw, bz, Lzb, Wh, Lhw, bh, Lhb,
                                 Mz, Mh, cz, chv);
    k_binwrite<<<WBLK, 256, 0, stream>>>(ei, ew, bincur8, er);
    k_deg<<<NBIN, 256, 0, stream>>>(er, binstart, dinv);
    k_accum<<<NBIN, 256, 0, stream>>>(er, binstart, dinv, x, Aout);
    k_dense<<<NN / 8, 256, 0, stream>>>(Aout, Mz, Mh, cz, chv, Wout, bout, out);
}